// Round 6
// baseline (4994.391 us; speedup 1.0000x reference)
//
#include <hip/hip_runtime.h>
#include <cstdint>
#include <cstddef>

#define NFILT 40
#define NBINS 257
#define HID   64
#define BB    64      // batch
#define TT    2000    // time
#define GATES 256     // 4*HID
#define MTOT  (BB*TT) // 128000 rows

// ---------- activations ----------
__device__ __forceinline__ float sigm(float x) {
  return 1.0f / (1.0f + __expf(-x));
}
__device__ __forceinline__ float tanh_(float x) {
  float e = __expf(-2.0f * fabsf(x));
  float r = (1.0f - e) / (1.0f + e);
  return copysignf(r, x);
}

// wave-wide broadcast of lane k's value via readlane (SALU/VALU, no LDS)
#define RL(x, k) __int_as_float(__builtin_amdgcn_readlane(__float_as_int(x), (k)))

// ---------- kernel 1: build fbank (40x257) + per-filter support bounds ----------
__global__ void k_fbank(const float* __restrict__ binpoints,
                        float* __restrict__ fbank,
                        int* __restrict__ lohi /*[2*NFILT]*/) {
  __shared__ float b[NFILT + 2];
  int tid = threadIdx.x;
  if (tid < NFILT + 2) b[tid] = binpoints[tid];
  __syncthreads();
  if (tid < NFILT) {
    if (tid == NFILT - 1) { lohi[tid] = 0; lohi[NFILT + tid] = 0; }
    else {
      int lo = (int)floorf(b[tid]);
      int hi = (int)floorf(b[tid + 2]);
      if (lo < 0) lo = 0;
      if (hi > NBINS) hi = NBINS;
      lohi[tid] = lo; lohi[NFILT + tid] = hi;
    }
  }
  for (int idx = tid; idx < NFILT * NBINS; idx += blockDim.x) {
    int f = idx / NBINS, i = idx - f * NBINS;
    float bj = b[f], bj1 = b[f + 1], bj2 = b[f + 2];
    float fb0 = floorf(bj), fb1 = floorf(bj1), fb2 = floorf(bj2);
    float fi = (float)i;
    bool rise = (fi >= fb0) && (fi < fb1);
    bool fall = (fi >= fb1) && (fi < fb2);
    float d1 = bj1 - bj;  d1 = (d1 > 0.f) ? d1 : 1.f;
    float d2 = bj2 - bj1; d2 = (d2 > 0.f) ? d2 : 1.f;
    float rv = (fi - bj)  / (d1 * d1);
    float fv = (bj2 - fi) / (d2 * d2);
    float v = fall ? fv : (rise ? rv : 0.f);
    if (f == NFILT - 1) v = 0.f;
    fbank[idx] = v;
  }
}

// ---------- kernel 2: featurize  h0[bt][f] = log(filt + 1e-10) ----------
__global__ __launch_bounds__(64) void k_feat(const float* __restrict__ x,
                                             const float* __restrict__ fbank,
                                             const int* __restrict__ lohi,
                                             float* __restrict__ h0) {
  int bt = blockIdx.x;
  __shared__ float xs[NBINS];
  const float* xr = x + (size_t)bt * NBINS;
  for (int i = threadIdx.x; i < NBINS; i += 64) xs[i] = xr[i];
  __syncthreads();
  int f = threadIdx.x;
  if (f < NFILT) {
    float acc = 0.f;
    int lo = lohi[f], hi = lohi[NFILT + f];
    for (int i = lo; i < hi; ++i) acc = fmaf(xs[i], fbank[f * NBINS + i], acc);
    float val = (f == 0) ? xs[0] : acc;
    h0[(size_t)bt * NFILT + f] = logf(val + 1e-10f);
  }
}

// ---------- kernel 3: fp32 GEMM  pre[d][m][g] = H[m][:]·W[d][g][:] + bih + bhh ----------
template <int K, int BK>
__global__ __launch_bounds__(256) void k_gemm(const float* __restrict__ Hm,   // [MTOT][K]
                                              const float* __restrict__ W,    // [2][256][K]
                                              const float* __restrict__ bih,  // [2][256]
                                              const float* __restrict__ bhh,  // [2][256]
                                              float* __restrict__ pre) {      // [2][MTOT][256]
  constexpr int BM = 128, BN = 64;
  __shared__ float Hs[BK][BM + 4];
  __shared__ float Ws[BK][BN + 4];
  const int d  = blockIdx.z;
  const int m0 = blockIdx.x * BM;
  const int g0 = blockIdx.y * BN;
  const int tid = threadIdx.x;
  const int tx = tid & 15, ty = tid >> 4;

  float acc[8][4];
#pragma unroll
  for (int r = 0; r < 8; ++r)
#pragma unroll
    for (int j = 0; j < 4; ++j) acc[r][j] = 0.f;

  for (int k0 = 0; k0 < K; k0 += BK) {
    constexpr int HL = BM * BK / 256;
#pragma unroll
    for (int i = 0; i < HL; ++i) {
      int flat = tid + i * 256;
      int r = flat / BK, kk = flat - r * BK;
      Hs[kk][r] = Hm[(size_t)(m0 + r) * K + k0 + kk];
    }
    constexpr int WL = BN * BK / 256;
#pragma unroll
    for (int i = 0; i < WL; ++i) {
      int flat = tid + i * 256;
      int r = flat / BK, kk = flat - r * BK;
      Ws[kk][r] = W[((size_t)d * GATES + g0 + r) * K + k0 + kk];
    }
    __syncthreads();
#pragma unroll
    for (int kk = 0; kk < BK; ++kk) {
      const float4 wv  = *(const float4*)&Ws[kk][tx * 4];
      const float4 hv0 = *(const float4*)&Hs[kk][ty * 8];
      const float4 hv1 = *(const float4*)&Hs[kk][ty * 8 + 4];
      const float hr[8] = {hv0.x, hv0.y, hv0.z, hv0.w, hv1.x, hv1.y, hv1.z, hv1.w};
#pragma unroll
      for (int r = 0; r < 8; ++r) {
        acc[r][0] = fmaf(hr[r], wv.x, acc[r][0]);
        acc[r][1] = fmaf(hr[r], wv.y, acc[r][1]);
        acc[r][2] = fmaf(hr[r], wv.z, acc[r][2]);
        acc[r][3] = fmaf(hr[r], wv.w, acc[r][3]);
      }
    }
    __syncthreads();
  }

  const int gcol = g0 + tx * 4;
  const float4 bi = *(const float4*)&bih[d * GATES + gcol];
  const float4 bh = *(const float4*)&bhh[d * GATES + gcol];
  const float bx = bi.x + bh.x, by = bi.y + bh.y, bz = bi.z + bh.z, bw = bi.w + bh.w;
#pragma unroll
  for (int r = 0; r < 8; ++r) {
    size_t m = (size_t)(m0 + ty * 8 + r);
    float4 o = {acc[r][0] + bx, acc[r][1] + by, acc[r][2] + bz, acc[r][3] + bw};
    *(float4*)&pre[((size_t)d * MTOT + m) * GATES + gcol] = o;
  }
}

// ---------- kernel 4: recurrent LSTM, 4 waves/(b,d), h in registers, readlane matvec ----------
// Thread g owns gate row g. Wave w = gate type (0:i 1:f 2:g 3:o); lane j = unit.
// h lives in a REGISTER: lane j of every wave holds h[j] (each wave redundantly
// does the c/h update for its lane's unit). The 64-wide h broadcast for the
// matvec is v_readlane -> SGPR -> v_fmac: zero LDS traffic on the h path.
// Only cross-wave exchange: activated gate values through parity-double-buffered
// abuf (1 ds_write + 4 ds_read_b32 per lane per step). Sync = raw asm
// "s_waitcnt lgkmcnt(0); s_barrier": no vmcnt drain, so the 4-deep HBM prefetch
// of pre stays in flight across steps.
// Race-freedom (1 barrier/step): a wave's lgkmcnt(0) before barrier t+1 waits for
// its parity-p reads of step t; the next parity-p write happens after barrier t+1.
__global__ __launch_bounds__(256, 1) void k_lstm4w(const float* __restrict__ pre, // [2][B*T][256]
                                                   const float* __restrict__ whh, // [2][256][64]
                                                   float* __restrict__ hout,      // [B][T][128]
                                                   float* __restrict__ out,       // [B][128]
                                                   int final_layer) {
  const int b = blockIdx.x, d = blockIdx.y;
  const int g = threadIdx.x;
  const int w = g >> 6;            // wave id == gate type
  const int j = g & 63;            // hidden unit (lane)
  __shared__ float abuf[2][GATES]; // activated gate values, parity double-buffered

  float wv[64];                    // 64 VGPRs: row g of whh[d]
  const float4* wr = (const float4*)(whh + ((size_t)d * GATES + g) * HID);
#pragma unroll
  for (int kk = 0; kk < 16; ++kk) {
    const float4 t4 = wr[kk];
    wv[4 * kk + 0] = t4.x; wv[4 * kk + 1] = t4.y;
    wv[4 * kk + 2] = t4.z; wv[4 * kk + 3] = t4.w;
  }

  float h_reg = 0.f;               // lane j holds h[j] (per-wave replica)
  float c = 0.f, sum = 0.f;
  __syncthreads();                 // one-time

  const size_t base = ((size_t)d * BB + b) * (size_t)TT;
  const int t0 = d ? (TT - 1) : 0;
  const int dt = d ? -1 : 1;
  const float* pp = pre + (base + (size_t)t0) * GATES + g;
  const ptrdiff_t pstr = (ptrdiff_t)dt * GATES;

  float pf0 = pp[0], pf1 = pp[pstr], pf2 = pp[pstr * 2], pf3 = pp[pstr * 3];

#define LSTM_STEP(TK, PAR, PF)                                                 \
  do {                                                                         \
    float a0 = (PF), a1 = 0.f, a2 = 0.f, a3 = 0.f;                             \
    _Pragma("unroll")                                                          \
    for (int k = 0; k < 64; k += 4) {                                          \
      a0 = fmaf(RL(h_reg, k + 0), wv[k + 0], a0);                              \
      a1 = fmaf(RL(h_reg, k + 1), wv[k + 1], a1);                              \
      a2 = fmaf(RL(h_reg, k + 2), wv[k + 2], a2);                              \
      a3 = fmaf(RL(h_reg, k + 3), wv[k + 3], a3);                              \
    }                                                                          \
    const float z = (a0 + a1) + (a2 + a3);                                     \
    const float act = (w == 2) ? tanh_(z) : sigm(z);  /* wave-uniform branch */ \
    abuf[PAR][g] = act;                                                        \
    asm volatile("s_waitcnt lgkmcnt(0)\n\ts_barrier" ::: "memory");            \
    const float ig = abuf[PAR][j],           fg = abuf[PAR][HID + j];          \
    const float gg = abuf[PAR][2 * HID + j], og = abuf[PAR][3 * HID + j];      \
    c = fmaf(fg, c, ig * gg);                                                  \
    h_reg = og * tanh_(c);                                                     \
    if (final_layer) sum += h_reg;                                             \
    else if (w == 0)                                                           \
      hout[((size_t)b * TT + (size_t)(t0 + dt * (TK))) * (2 * HID) + d * HID + j] = h_reg; \
  } while (0)

  for (int t = 0; t < TT; t += 4) {
    LSTM_STEP(t + 0, 0, pf0);
    { int ip = t + 4; if (ip >= TT) ip = 0; pf0 = pp[pstr * (ptrdiff_t)ip]; }
    LSTM_STEP(t + 1, 1, pf1);
    { int ip = t + 5; if (ip >= TT) ip = 0; pf1 = pp[pstr * (ptrdiff_t)ip]; }
    LSTM_STEP(t + 2, 0, pf2);
    { int ip = t + 6; if (ip >= TT) ip = 0; pf2 = pp[pstr * (ptrdiff_t)ip]; }
    LSTM_STEP(t + 3, 1, pf3);
    { int ip = t + 7; if (ip >= TT) ip = 0; pf3 = pp[pstr * (ptrdiff_t)ip]; }
  }
#undef LSTM_STEP

  if (final_layer && w == 0) out[b * (2 * HID) + d * HID + j] = sum * (1.0f / (float)TT);
}

// ---------- launch ----------
extern "C" void kernel_launch(void* const* d_in, const int* in_sizes, int n_in,
                              void* d_out, int out_size, void* d_ws, size_t ws_size,
                              hipStream_t stream) {
  const float* x         = (const float*)d_in[0];
  const float* binpoints = (const float*)d_in[1];
  const float* w_ih[3] = {(const float*)d_in[2], (const float*)d_in[6],  (const float*)d_in[10]};
  const float* w_hh[3] = {(const float*)d_in[3], (const float*)d_in[7],  (const float*)d_in[11]};
  const float* b_ih[3] = {(const float*)d_in[4], (const float*)d_in[8],  (const float*)d_in[12]};
  const float* b_hh[3] = {(const float*)d_in[5], (const float*)d_in[9],  (const float*)d_in[13]};
  float* out = (float*)d_out;

  // workspace layout (~349 MB):
  //   pre  : 2*MTOT*256 f32 = 262,144,000 B
  //   Hbuf : MTOT*128 f32   =  65,536,000 B
  //   h0   : MTOT*40 f32    =  20,480,000 B
  //   fbank: 40*257 f32, lohi: 80 i32
  float* pre   = (float*)d_ws;
  float* Hbuf  = pre  + (size_t)2 * MTOT * GATES;
  float* h0    = Hbuf + (size_t)MTOT * 128;
  float* fbank = h0   + (size_t)MTOT * NFILT;
  int*   lohi  = (int*)(fbank + NFILT * NBINS);

  k_fbank<<<1, 256, 0, stream>>>(binpoints, fbank, lohi);
  k_feat<<<MTOT, 64, 0, stream>>>(x, fbank, lohi, h0);

  // layer 0 (K=40)
  k_gemm<40, 40><<<dim3(MTOT / 128, GATES / 64, 2), 256, 0, stream>>>(h0, w_ih[0], b_ih[0], b_hh[0], pre);
  k_lstm4w<<<dim3(BB, 2), 256, 0, stream>>>(pre, w_hh[0], Hbuf, out, 0);

  // layer 1 (K=128)
  k_gemm<128, 32><<<dim3(MTOT / 128, GATES / 64, 2), 256, 0, stream>>>(Hbuf, w_ih[1], b_ih[1], b_hh[1], pre);
  k_lstm4w<<<dim3(BB, 2), 256, 0, stream>>>(pre, w_hh[1], Hbuf, out, 0);

  // layer 2 (K=128)
  k_gemm<128, 32><<<dim3(MTOT / 128, GATES / 64, 2), 256, 0, stream>>>(Hbuf, w_ih[2], b_ih[2], b_hh[2], pre);
  k_lstm4w<<<dim3(BB, 2), 256, 0, stream>>>(pre, w_hh[2], Hbuf, out, 1);
}

// Round 7
// 4927.942 us; speedup vs baseline: 1.0135x; 1.0135x over previous
//
#include <hip/hip_runtime.h>
#include <cstdint>
#include <cstddef>

#define NFILT 40
#define NBINS 257
#define HID   64
#define BB    64      // batch
#define TT    2000    // time
#define GATES 256     // 4*HID
#define MTOT  (BB*TT) // 128000 rows

// ---------- activations ----------
__device__ __forceinline__ float sigm(float x) {
  return 1.0f / (1.0f + __expf(-x));
}
__device__ __forceinline__ float tanh_(float x) {
  float e = __expf(-2.0f * fabsf(x));
  float r = (1.0f - e) / (1.0f + e);
  return copysignf(r, x);
}

// wave-wide broadcast of lane k's value via readlane (SALU/VALU, no LDS)
#define RL(x, k) __int_as_float(__builtin_amdgcn_readlane(__float_as_int(x), (k)))

// ---------- kernel 1: build fbank (40x257) + per-filter support bounds ----------
__global__ void k_fbank(const float* __restrict__ binpoints,
                        float* __restrict__ fbank,
                        int* __restrict__ lohi /*[2*NFILT]*/) {
  __shared__ float b[NFILT + 2];
  int tid = threadIdx.x;
  if (tid < NFILT + 2) b[tid] = binpoints[tid];
  __syncthreads();
  if (tid < NFILT) {
    if (tid == NFILT - 1) { lohi[tid] = 0; lohi[NFILT + tid] = 0; }
    else {
      int lo = (int)floorf(b[tid]);
      int hi = (int)floorf(b[tid + 2]);
      if (lo < 0) lo = 0;
      if (hi > NBINS) hi = NBINS;
      lohi[tid] = lo; lohi[NFILT + tid] = hi;
    }
  }
  for (int idx = tid; idx < NFILT * NBINS; idx += blockDim.x) {
    int f = idx / NBINS, i = idx - f * NBINS;
    float bj = b[f], bj1 = b[f + 1], bj2 = b[f + 2];
    float fb0 = floorf(bj), fb1 = floorf(bj1), fb2 = floorf(bj2);
    float fi = (float)i;
    bool rise = (fi >= fb0) && (fi < fb1);
    bool fall = (fi >= fb1) && (fi < fb2);
    float d1 = bj1 - bj;  d1 = (d1 > 0.f) ? d1 : 1.f;
    float d2 = bj2 - bj1; d2 = (d2 > 0.f) ? d2 : 1.f;
    float rv = (fi - bj)  / (d1 * d1);
    float fv = (bj2 - fi) / (d2 * d2);
    float v = fall ? fv : (rise ? rv : 0.f);
    if (f == NFILT - 1) v = 0.f;
    fbank[idx] = v;
  }
}

// ---------- kernel 2: featurize  h0[bt][f] = log(filt + 1e-10) ----------
__global__ __launch_bounds__(64) void k_feat(const float* __restrict__ x,
                                             const float* __restrict__ fbank,
                                             const int* __restrict__ lohi,
                                             float* __restrict__ h0) {
  int bt = blockIdx.x;
  __shared__ float xs[NBINS];
  const float* xr = x + (size_t)bt * NBINS;
  for (int i = threadIdx.x; i < NBINS; i += 64) xs[i] = xr[i];
  __syncthreads();
  int f = threadIdx.x;
  if (f < NFILT) {
    float acc = 0.f;
    int lo = lohi[f], hi = lohi[NFILT + f];
    for (int i = lo; i < hi; ++i) acc = fmaf(xs[i], fbank[f * NBINS + i], acc);
    float val = (f == 0) ? xs[0] : acc;
    h0[(size_t)bt * NFILT + f] = logf(val + 1e-10f);
  }
}

// ---------- kernel 3: fp32 GEMM  pre[d][m][g] = H[m][:]·W[d][g][:] + bih + bhh ----------
template <int K, int BK>
__global__ __launch_bounds__(256) void k_gemm(const float* __restrict__ Hm,   // [MTOT][K]
                                              const float* __restrict__ W,    // [2][256][K]
                                              const float* __restrict__ bih,  // [2][256]
                                              const float* __restrict__ bhh,  // [2][256]
                                              float* __restrict__ pre) {      // [2][MTOT][256]
  constexpr int BM = 128, BN = 64;
  __shared__ float Hs[BK][BM + 4];
  __shared__ float Ws[BK][BN + 4];
  const int d  = blockIdx.z;
  const int m0 = blockIdx.x * BM;
  const int g0 = blockIdx.y * BN;
  const int tid = threadIdx.x;
  const int tx = tid & 15, ty = tid >> 4;

  float acc[8][4];
#pragma unroll
  for (int r = 0; r < 8; ++r)
#pragma unroll
    for (int j = 0; j < 4; ++j) acc[r][j] = 0.f;

  for (int k0 = 0; k0 < K; k0 += BK) {
    constexpr int HL = BM * BK / 256;
#pragma unroll
    for (int i = 0; i < HL; ++i) {
      int flat = tid + i * 256;
      int r = flat / BK, kk = flat - r * BK;
      Hs[kk][r] = Hm[(size_t)(m0 + r) * K + k0 + kk];
    }
    constexpr int WL = BN * BK / 256;
#pragma unroll
    for (int i = 0; i < WL; ++i) {
      int flat = tid + i * 256;
      int r = flat / BK, kk = flat - r * BK;
      Ws[kk][r] = W[((size_t)d * GATES + g0 + r) * K + k0 + kk];
    }
    __syncthreads();
#pragma unroll
    for (int kk = 0; kk < BK; ++kk) {
      const float4 wv  = *(const float4*)&Ws[kk][tx * 4];
      const float4 hv0 = *(const float4*)&Hs[kk][ty * 8];
      const float4 hv1 = *(const float4*)&Hs[kk][ty * 8 + 4];
      const float hr[8] = {hv0.x, hv0.y, hv0.z, hv0.w, hv1.x, hv1.y, hv1.z, hv1.w};
#pragma unroll
      for (int r = 0; r < 8; ++r) {
        acc[r][0] = fmaf(hr[r], wv.x, acc[r][0]);
        acc[r][1] = fmaf(hr[r], wv.y, acc[r][1]);
        acc[r][2] = fmaf(hr[r], wv.z, acc[r][2]);
        acc[r][3] = fmaf(hr[r], wv.w, acc[r][3]);
      }
    }
    __syncthreads();
  }

  const int gcol = g0 + tx * 4;
  const float4 bi = *(const float4*)&bih[d * GATES + gcol];
  const float4 bh = *(const float4*)&bhh[d * GATES + gcol];
  const float bx = bi.x + bh.x, by = bi.y + bh.y, bz = bi.z + bh.z, bw = bi.w + bh.w;
#pragma unroll
  for (int r = 0; r < 8; ++r) {
    size_t m = (size_t)(m0 + ty * 8 + r);
    float4 o = {acc[r][0] + bx, acc[r][1] + by, acc[r][2] + bz, acc[r][3] + bw};
    *(float4*)&pre[((size_t)d * MTOT + m) * GATES + gcol] = o;
  }
}

// ---------- kernel 4: recurrent LSTM, 4 waves/(b,d), h in registers, readlane matvec ----------
// Thread g owns gate row g. Wave w = gate type (0:i 1:f 2:g 3:o); lane j = unit.
// h lives in a REGISTER: lane j of every wave holds h[j] (each wave redundantly
// does the c/h update for its lane's unit). The 64-wide h broadcast for the
// matvec is v_readlane -> SGPR -> v_fmac: zero LDS traffic on the h path.
// The 64 weights/lane are PINNED into VGPRs with an opaque asm "+v" constraint;
// without this the compiler rematerializes the weight loads inside the loop
// (rounds 1-6 all showed VGPR_Count ~44-52, impossible for 64 live floats).
// Only cross-wave exchange: activated gate values through parity-double-buffered
// abuf. Sync = raw asm "s_waitcnt lgkmcnt(0); s_barrier": no vmcnt drain, so the
// 4-deep HBM prefetch of pre stays in flight across steps.
// Race-freedom (1 barrier/step): a wave's lgkmcnt(0) before barrier t+1 waits for
// its parity-p reads of step t; the next parity-p write happens after barrier t+1.
__global__ __launch_bounds__(256, 1) void k_lstm4w(const float* __restrict__ pre, // [2][B*T][256]
                                                   const float* __restrict__ whh, // [2][256][64]
                                                   float* __restrict__ hout,      // [B][T][128]
                                                   float* __restrict__ out,       // [B][128]
                                                   int final_layer) {
  const int b = blockIdx.x, d = blockIdx.y;
  const int g = threadIdx.x;
  const int w = g >> 6;            // wave id == gate type
  const int j = g & 63;            // hidden unit (lane)
  __shared__ float abuf[2][GATES]; // activated gate values, parity double-buffered

  float wv[64];                    // 64 VGPRs: row g of whh[d]
  const float4* wr = (const float4*)(whh + ((size_t)d * GATES + g) * HID);
#pragma unroll
  for (int kk = 0; kk < 16; ++kk) {
    const float4 t4 = wr[kk];
    wv[4 * kk + 0] = t4.x; wv[4 * kk + 1] = t4.y;
    wv[4 * kk + 2] = t4.z; wv[4 * kk + 3] = t4.w;
  }
  // pin each weight into a VGPR: opaque asm forbids remat/spill of the array
#pragma unroll
  for (int kk = 0; kk < 64; ++kk) {
    asm volatile("" : "+v"(wv[kk]));
  }

  float h_reg = 0.f;               // lane j holds h[j] (per-wave replica)
  float c = 0.f, sum = 0.f;
  __syncthreads();                 // one-time

  const size_t base = ((size_t)d * BB + b) * (size_t)TT;
  const int t0 = d ? (TT - 1) : 0;
  const int dt = d ? -1 : 1;
  const float* pp = pre + (base + (size_t)t0) * GATES + g;
  const ptrdiff_t pstr = (ptrdiff_t)dt * GATES;

  float pf0 = pp[0], pf1 = pp[pstr], pf2 = pp[pstr * 2], pf3 = pp[pstr * 3];

#define LSTM_STEP(TK, PAR, PF)                                                 \
  do {                                                                         \
    float a0 = (PF), a1 = 0.f, a2 = 0.f, a3 = 0.f;                             \
    _Pragma("unroll")                                                          \
    for (int k = 0; k < 64; k += 4) {                                          \
      a0 = fmaf(RL(h_reg, k + 0), wv[k + 0], a0);                              \
      a1 = fmaf(RL(h_reg, k + 1), wv[k + 1], a1);                              \
      a2 = fmaf(RL(h_reg, k + 2), wv[k + 2], a2);                              \
      a3 = fmaf(RL(h_reg, k + 3), wv[k + 3], a3);                              \
    }                                                                          \
    const float z = (a0 + a1) + (a2 + a3);                                     \
    const float act = (w == 2) ? tanh_(z) : sigm(z);  /* wave-uniform branch */ \
    abuf[PAR][g] = act;                                                        \
    asm volatile("s_waitcnt lgkmcnt(0)\n\ts_barrier" ::: "memory");            \
    const float ig = abuf[PAR][j],           fg = abuf[PAR][HID + j];          \
    const float gg = abuf[PAR][2 * HID + j], og = abuf[PAR][3 * HID + j];      \
    c = fmaf(fg, c, ig * gg);                                                  \
    h_reg = og * tanh_(c);                                                     \
    if (final_layer) sum += h_reg;                                             \
    else if (w == 0)                                                           \
      hout[((size_t)b * TT + (size_t)(t0 + dt * (TK))) * (2 * HID) + d * HID + j] = h_reg; \
  } while (0)

  for (int t = 0; t < TT; t += 4) {
    LSTM_STEP(t + 0, 0, pf0);
    { int ip = t + 4; if (ip >= TT) ip = 0; pf0 = pp[pstr * (ptrdiff_t)ip]; }
    LSTM_STEP(t + 1, 1, pf1);
    { int ip = t + 5; if (ip >= TT) ip = 0; pf1 = pp[pstr * (ptrdiff_t)ip]; }
    LSTM_STEP(t + 2, 0, pf2);
    { int ip = t + 6; if (ip >= TT) ip = 0; pf2 = pp[pstr * (ptrdiff_t)ip]; }
    LSTM_STEP(t + 3, 1, pf3);
    { int ip = t + 7; if (ip >= TT) ip = 0; pf3 = pp[pstr * (ptrdiff_t)ip]; }
  }
#undef LSTM_STEP

  if (final_layer && w == 0) out[b * (2 * HID) + d * HID + j] = sum * (1.0f / (float)TT);
}

// ---------- launch ----------
extern "C" void kernel_launch(void* const* d_in, const int* in_sizes, int n_in,
                              void* d_out, int out_size, void* d_ws, size_t ws_size,
                              hipStream_t stream) {
  const float* x         = (const float*)d_in[0];
  const float* binpoints = (const float*)d_in[1];
  const float* w_ih[3] = {(const float*)d_in[2], (const float*)d_in[6],  (const float*)d_in[10]};
  const float* w_hh[3] = {(const float*)d_in[3], (const float*)d_in[7],  (const float*)d_in[11]};
  const float* b_ih[3] = {(const float*)d_in[4], (const float*)d_in[8],  (const float*)d_in[12]};
  const float* b_hh[3] = {(const float*)d_in[5], (const float*)d_in[9],  (const float*)d_in[13]};
  float* out = (float*)d_out;

  // workspace layout (~349 MB):
  //   pre  : 2*MTOT*256 f32 = 262,144,000 B
  //   Hbuf : MTOT*128 f32   =  65,536,000 B
  //   h0   : MTOT*40 f32    =  20,480,000 B
  //   fbank: 40*257 f32, lohi: 80 i32
  float* pre   = (float*)d_ws;
  float* Hbuf  = pre  + (size_t)2 * MTOT * GATES;
  float* h0    = Hbuf + (size_t)MTOT * 128;
  float* fbank = h0   + (size_t)MTOT * NFILT;
  int*   lohi  = (int*)(fbank + NFILT * NBINS);

  k_fbank<<<1, 256, 0, stream>>>(binpoints, fbank, lohi);
  k_feat<<<MTOT, 64, 0, stream>>>(x, fbank, lohi, h0);

  // layer 0 (K=40)
  k_gemm<40, 40><<<dim3(MTOT / 128, GATES / 64, 2), 256, 0, stream>>>(h0, w_ih[0], b_ih[0], b_hh[0], pre);
  k_lstm4w<<<dim3(BB, 2), 256, 0, stream>>>(pre, w_hh[0], Hbuf, out, 0);

  // layer 1 (K=128)
  k_gemm<128, 32><<<dim3(MTOT / 128, GATES / 64, 2), 256, 0, stream>>>(Hbuf, w_ih[1], b_ih[1], b_hh[1], pre);
  k_lstm4w<<<dim3(BB, 2), 256, 0, stream>>>(pre, w_hh[1], Hbuf, out, 0);

  // layer 2 (K=128)
  k_gemm<128, 32><<<dim3(MTOT / 128, GATES / 64, 2), 256, 0, stream>>>(Hbuf, w_ih[2], b_ih[2], b_hh[2], pre);
  k_lstm4w<<<dim3(BB, 2), 256, 0, stream>>>(pre, w_hh[2], Hbuf, out, 1);
}